// Round 6
// baseline (1128.372 us; speedup 1.0000x reference)
//
#include <hip/hip_runtime.h>
#include <hip/hip_bf16.h>
#include <stdint.h>

typedef __hip_bfloat16 bf16;
typedef short bf16x8 __attribute__((ext_vector_type(8)));
typedef float f32x4 __attribute__((ext_vector_type(4)));

typedef __attribute__((address_space(1))) const unsigned int as1_uint;
typedef __attribute__((address_space(3))) unsigned int as3_uint;

__device__ __forceinline__ void async_copy16(const void* g, void* l) {
    __builtin_amdgcn_global_load_lds((as1_uint*)g, (as3_uint*)l, 16, 0, 0);
}

__device__ __forceinline__ float b2f(unsigned short u) {
    union { unsigned int i; float f; } c; c.i = ((unsigned int)u) << 16; return c.f;
}
__device__ __forceinline__ unsigned short f2b(float f) {
    union { float f; unsigned int i; } c; c.f = f;
    unsigned int i = c.i;
    i += 0x7fffu + ((i >> 16) & 1u);   // round-to-nearest-even
    return (unsigned short)(i >> 16);
}

// ---------------------------------------------------------------------------
// f32 -> bf16 conversion (weights). 8 elements/thread.
// ---------------------------------------------------------------------------
__global__ __launch_bounds__(256)
void cvt_kernel(const float* __restrict__ in, bf16* __restrict__ out)
{
    const int i = (blockIdx.x * 256 + threadIdx.x) * 8;
    const float4 a = *(const float4*)(in + i);
    const float4 b = *(const float4*)(in + i + 4);
    union { uint4 v; unsigned short s[8]; } u;
    u.s[0] = f2b(a.x); u.s[1] = f2b(a.y); u.s[2] = f2b(a.z); u.s[3] = f2b(a.w);
    u.s[4] = f2b(b.x); u.s[5] = f2b(b.y); u.s[6] = f2b(b.z); u.s[7] = f2b(b.w);
    *(uint4*)((unsigned short*)out + i) = u.v;
}

// ---------------------------------------------------------------------------
// LayerNorm: one wave per row of 512; block = 4 rows. f32 in, bf16 out.
// ---------------------------------------------------------------------------
__global__ __launch_bounds__(256)
void ln_kernel(const float* __restrict__ x, const float* __restrict__ g,
               const float* __restrict__ beta, bf16* __restrict__ out)
{
    const int w = threadIdx.x >> 6, l = threadIdx.x & 63;
    const int n = blockIdx.x * 4 + w;

    const float* xr = x + (size_t)n * 512 + l * 8;
    const float4 a = *(const float4*)xr;
    const float4 b = *(const float4*)(xr + 4);
    float f[8] = {a.x, a.y, a.z, a.w, b.x, b.y, b.z, b.w};

    float s = 0.f, q = 0.f;
#pragma unroll
    for (int i = 0; i < 8; ++i) { s += f[i]; q += f[i] * f[i]; }
#pragma unroll
    for (int o = 32; o > 0; o >>= 1) { s += __shfl_xor(s, o); q += __shfl_xor(q, o); }
    const float mean = s * (1.f / 512.f);
    const float var  = q * (1.f / 512.f) - mean * mean;
    const float rstd = rsqrtf(var + 1e-5f);

    const float4 g0 = *(const float4*)(g + l * 8);
    const float4 g1 = *(const float4*)(g + l * 8 + 4);
    const float4 b0 = *(const float4*)(beta + l * 8);
    const float4 b1 = *(const float4*)(beta + l * 8 + 4);
    const float gg[8] = {g0.x,g0.y,g0.z,g0.w,g1.x,g1.y,g1.z,g1.w};
    const float bb[8] = {b0.x,b0.y,b0.z,b0.w,b1.x,b1.y,b1.z,b1.w};

    union { uint4 v; unsigned short s[8]; } o;
#pragma unroll
    for (int i = 0; i < 8; ++i)
        o.s[i] = f2b((f[i] - mean) * rstd * gg[i] + bb[i]);
    *(uint4*)((unsigned short*)out + (size_t)n * 512 + l * 8) = o.v;
}

// ---------------------------------------------------------------------------
// Per-node attention over heads. qkv [n][1536] = q(8x64),k(8x64),v(8x64).
// ---------------------------------------------------------------------------
__global__ __launch_bounds__(256)
void attn_kernel(const bf16* __restrict__ qkv, bf16* __restrict__ out)
{
    __shared__ unsigned short sm[4][1536];
    const int w = threadIdx.x >> 6, l = threadIdx.x & 63;
    const int n = blockIdx.x * 4 + w;

    const uint4* src = (const uint4*)((const unsigned short*)qkv + (size_t)n * 1536);
    uint4* dst = (uint4*)sm[w];
#pragma unroll
    for (int i = 0; i < 3; ++i) dst[i * 64 + l] = src[i * 64 + l];
    __syncthreads();

    const int h = l >> 3, gi = l & 7;
    const unsigned short* qrow = sm[w] + h * 64;
    const unsigned short* krow = sm[w] + 512 + gi * 64;
    float s = 0.f;
#pragma unroll
    for (int jj = 0; jj < 8; ++jj) {
        union { uint4 v; unsigned short s8[8]; } qa, ka;
        qa.v = *(const uint4*)(qrow + jj * 8);
        ka.v = *(const uint4*)(krow + jj * 8);
#pragma unroll
        for (int j = 0; j < 8; ++j) s += b2f(qa.s8[j]) * b2f(ka.s8[j]);
    }
    s *= 0.125f;   // 1/sqrt(64)

    float m = s;
#pragma unroll
    for (int o = 1; o < 8; o <<= 1) m = fmaxf(m, __shfl_xor(m, o));
    float e = __expf(s - m);
    float d = e;
#pragma unroll
    for (int o = 1; o < 8; o <<= 1) d += __shfl_xor(d, o);
    const float p = e / d;

    float acc[8];
#pragma unroll
    for (int j = 0; j < 8; ++j) acc[j] = 0.f;
    const int j8 = (l & 7) * 8;
#pragma unroll
    for (int gg = 0; gg < 8; ++gg) {
        const float pg = __shfl(p, (l & 56) | gg);
        union { uint4 v; unsigned short s8[8]; } va;
        va.v = *(const uint4*)(sm[w] + 1024 + gg * 64 + j8);
#pragma unroll
        for (int j = 0; j < 8; ++j) acc[j] += pg * b2f(va.s8[j]);
    }
    union { uint4 v; unsigned short s8[8]; } o;
#pragma unroll
    for (int j = 0; j < 8; ++j) o.s8[j] = f2b(acc[j]);
    *(uint4*)((unsigned short*)out + (size_t)n * 512 + h * 64 + j8) = o.v;
}

// ---------------------------------------------------------------------------
// GEMM  C = A[M][K] * B^T (+f32 bias, +f32 res, relu) — m201 8-phase port.
// Unchanged from r4 except the prologue interleaves A/B so vmcnt(4)
// retires ALL of T0 before the first reads.
// ---------------------------------------------------------------------------
#define EPI_PLAIN 0
#define EPI_RES   1
#define EPI_RELU  2

template<int MODE>
__global__ __launch_bounds__(512, 2)
void gemm_bt(const bf16* __restrict__ A,
             const bf16* __restrict__ B0, const bf16* __restrict__ B1,
             const bf16* __restrict__ B2,
             const float* __restrict__ bias0, const float* __restrict__ bias1,
             const float* __restrict__ bias2,
             const float* __restrict__ res,
             void* __restrict__ C,
             int K, int Nper, int ldc)
{
    __shared__ bf16 As[2][2][8192];
    __shared__ bf16 Bs[2][2][8192];

    const int tid = threadIdx.x;
    const int w = tid >> 6, l = tid & 63;

    const int nbx = gridDim.x;
    const int nwg = nbx * (int)gridDim.y;
    int lid = blockIdx.y * nbx + blockIdx.x;
    {
        const int q = nwg >> 3, r = nwg & 7;
        const int xcd = lid & 7, idx = lid >> 3;
        lid = (xcd < r ? xcd * (q + 1) : r * (q + 1) + (xcd - r) * q) + idx;
    }
    const int bx = lid % nbx, by = lid / nbx;

    const int rowBase = by * 256;
    const int colBase = bx * 256;
    const int sel = colBase / Nper;
    const bf16*  B    = (sel == 0) ? B0 : (sel == 1) ? B1 : B2;
    const float* bias = (sel == 0) ? bias0 : (sel == 1) ? bias1 : bias2;
    const int colInB = colBase - sel * Nper;

    const bf16* Ag = A + (size_t)rowBase * K;
    const bf16* Bg = B + (size_t)colInB * K;

    const int wr = w >> 2, wc = w & 3;
    const int ml = l & 15;
    const int kc = l >> 4;
    const int rdoff = ((kc ^ ((ml >> 1) & 3)) << 3);

    const int s_row = l >> 2;
    const int s_koff = (((l & 3) ^ ((l >> 3) & 3)) << 3);

    auto stA = [&](int t, int half) {
#pragma unroll
        for (int c = 0; c < 2; ++c) {
            const int q = (w << 1) | c;
            const int p = q >> 3, rr = q & 7;
            const bf16* src = Ag + (size_t)(half * 128 + rr * 16 + s_row) * K
                            + (t << 6) + p * 32 + s_koff;
            async_copy16(src, &As[t & 1][half][q << 9]);
        }
    };
    auto stB = [&](int t, int half) {
#pragma unroll
        for (int c = 0; c < 2; ++c) {
            const int q = (w << 1) | c;
            const int p = q >> 3, rr = q & 7;
            const bf16* src = Bg + (size_t)(half * 128 + rr * 16 + s_row) * K
                            + (t << 6) + p * 32 + s_koff;
            async_copy16(src, &Bs[t & 1][half][q << 9]);
        }
    };

    const int bRow = ((wc & 1) << 6) + ml;
    const int bHalf = wc >> 1;

    f32x4 acc[8][4];
#pragma unroll
    for (int i = 0; i < 8; ++i)
#pragma unroll
        for (int j = 0; j < 4; ++j) acc[i][j] = (f32x4)(0.f);

    bf16x8 af[4][2], bf[4][2];

#define LDA(SLOT, MI, KS) \
    (*(const bf16x8*)(&As[SLOT][wr][(KS) * 4096 + ((MI) * 16 + ml) * 32 + rdoff]))
#define LDB(SLOT, NI, KS) \
    (*(const bf16x8*)(&Bs[SLOT][bHalf][(KS) * 4096 + (bRow + (NI) * 16) * 32 + rdoff]))

#define MMQ(MG, NG) \
    do { \
        _Pragma("unroll") \
        for (int mi = 0; mi < 4; ++mi) \
        _Pragma("unroll") \
        for (int nj = 0; nj < 2; ++nj) \
        _Pragma("unroll") \
        for (int ks = 0; ks < 2; ++ks) \
            acc[(MG)*4+mi][(NG)*2+nj] = __builtin_amdgcn_mfma_f32_16x16x32_bf16( \
                af[mi][ks], bf[(NG)*2+nj][ks], acc[(MG)*4+mi][(NG)*2+nj], 0, 0, 0); \
    } while (0)

#define SYNC_IN()  do { __builtin_amdgcn_s_barrier(); \
                        __builtin_amdgcn_sched_barrier(0); \
                        asm volatile("s_waitcnt lgkmcnt(0)" ::: "memory"); \
                        __builtin_amdgcn_sched_barrier(0); } while (0)
#define SYNC_OUT() do { __builtin_amdgcn_s_barrier(); \
                        __builtin_amdgcn_sched_barrier(0); } while (0)

    const int NT = K >> 6;
    const int NI = NT >> 1;

    // prologue: interleave A/B so vmcnt(4) retires ALL of T0.
    stA(0, 0); stB(0, 0); stA(0, 1); stB(0, 1);
    stA(1, 0); stB(1, 0);
    asm volatile("s_waitcnt vmcnt(4)" ::: "memory");
    __builtin_amdgcn_s_barrier();
    __builtin_amdgcn_sched_barrier(0);

    for (int i = 0; i < NI; ++i) {
        const int t1 = 2 * i + 1;
        const bool pf = (t1 + 1 < NT);

#pragma unroll
        for (int mi = 0; mi < 4; ++mi) { af[mi][0] = LDA(0, mi, 0); af[mi][1] = LDA(0, mi, 1); }
#pragma unroll
        for (int nj = 0; nj < 2; ++nj) { bf[nj][0] = LDB(0, nj, 0); bf[nj][1] = LDB(0, nj, 1); }
        stA(t1, 1);
        SYNC_IN();
        __builtin_amdgcn_s_setprio(1); MMQ(0, 0); __builtin_amdgcn_s_setprio(0);
        SYNC_OUT();

#pragma unroll
        for (int nj = 2; nj < 4; ++nj) { bf[nj][0] = LDB(0, nj, 0); bf[nj][1] = LDB(0, nj, 1); }
        stB(t1, 1);
        SYNC_IN();
        __builtin_amdgcn_s_setprio(1); MMQ(0, 1); __builtin_amdgcn_s_setprio(0);
        SYNC_OUT();

#pragma unroll
        for (int mi = 0; mi < 4; ++mi) { af[mi][0] = LDA(0, mi + 4, 0); af[mi][1] = LDA(0, mi + 4, 1); }
        if (pf) stB(t1 + 1, 0);
        SYNC_IN();
        __builtin_amdgcn_s_setprio(1); MMQ(1, 0); __builtin_amdgcn_s_setprio(0);
        SYNC_OUT();

        if (pf) stB(t1 + 1, 1);
        __builtin_amdgcn_s_barrier();
        __builtin_amdgcn_sched_barrier(0);
        __builtin_amdgcn_s_setprio(1); MMQ(1, 1); __builtin_amdgcn_s_setprio(0);
        if (pf) asm volatile("s_waitcnt vmcnt(4)" ::: "memory");
        else    asm volatile("s_waitcnt vmcnt(0)" ::: "memory");
        SYNC_OUT();

#pragma unroll
        for (int mi = 0; mi < 4; ++mi) { af[mi][0] = LDA(1, mi, 0); af[mi][1] = LDA(1, mi, 1); }
#pragma unroll
        for (int nj = 0; nj < 2; ++nj) { bf[nj][0] = LDB(1, nj, 0); bf[nj][1] = LDB(1, nj, 1); }
        if (pf) stA(t1 + 1, 0);
        SYNC_IN();
        __builtin_amdgcn_s_setprio(1); MMQ(0, 0); __builtin_amdgcn_s_setprio(0);
        SYNC_OUT();

#pragma unroll
        for (int nj = 2; nj < 4; ++nj) { bf[nj][0] = LDB(1, nj, 0); bf[nj][1] = LDB(1, nj, 1); }
        if (pf) stA(t1 + 1, 1);
        SYNC_IN();
        __builtin_amdgcn_s_setprio(1); MMQ(0, 1); __builtin_amdgcn_s_setprio(0);
        SYNC_OUT();

#pragma unroll
        for (int mi = 0; mi < 4; ++mi) { af[mi][0] = LDA(1, mi + 4, 0); af[mi][1] = LDA(1, mi + 4, 1); }
        if (pf) stB(t1 + 2, 0);
        SYNC_IN();
        __builtin_amdgcn_s_setprio(1); MMQ(1, 0); __builtin_amdgcn_s_setprio(0);
        SYNC_OUT();

        if (pf) stA(t1 + 2, 0);
        __builtin_amdgcn_s_barrier();
        __builtin_amdgcn_sched_barrier(0);
        __builtin_amdgcn_s_setprio(1); MMQ(1, 1); __builtin_amdgcn_s_setprio(0);
        if (pf) asm volatile("s_waitcnt vmcnt(4)" ::: "memory");
        if (i < NI - 1) SYNC_OUT();
    }

    float bv[4];
#pragma unroll
    for (int ni = 0; ni < 4; ++ni)
        bv[ni] = bias[colInB + (wc << 6) + (ni << 4) + ml];

#pragma unroll
    for (int mi = 0; mi < 8; ++mi) {
#pragma unroll
        for (int r4 = 0; r4 < 4; ++r4) {
            const int row = rowBase + (wr << 7) + (mi << 4) + (kc << 2) + r4;
            const size_t rowoff = (size_t)row * ldc;
#pragma unroll
            for (int ni = 0; ni < 4; ++ni) {
                const int gcol = colBase + (wc << 6) + (ni << 4) + ml;
                float v = acc[mi][ni][r4] + bv[ni];
                if (MODE == EPI_RELU) v = fmaxf(v, 0.f);
                if (MODE == EPI_RES) {
                    v += res[rowoff + gcol];
                    ((float*)C)[rowoff + gcol] = v;
                } else {
                    ((unsigned short*)C)[rowoff + gcol] = f2b(v);
                }
            }
        }
    }
#undef LDA
#undef LDB
#undef MMQ
#undef SYNC_IN
#undef SYNC_OUT
}

// ---------------------------------------------------------------------------
// Fused FFN: out = x2 + relu(h2 @ W1^T + b1) @ W2^T + b2, in-place on x2.
// Per block: 64 nodes. h2[64][512] resident in LDS (plane layout + XOR chunk
// swizzle, staged via pre-swizzled-source global_load_lds). 8 super-iters s:
//   p-phase: wave w computes p^T[32 ff1][64 node] for ff1 = s*256+w*32..+32
//            via mfma(af=W1 frags from L2, bfr=h2 frags from LDS), K=512.
//            +b1, relu, bf16-pack, write to ps[s&1][node][ff1local] with
//            col ^= (node&7)<<3 swizzle.
//   barrier; out-phase: wave w owns oc = w*64..+64:
//            acc2 += mfma(af2=W2 frags from L2, bfr2=p frags from LDS).
//   barrier (dbuf ps).
// Epilogue: out[node][oc] = acc2 + x2 + b2, float4 in-place.
// ff1 never touches global memory.
// ---------------------------------------------------------------------------
__global__ __launch_bounds__(512, 1)
void ffn_fused(const bf16* __restrict__ h2,   // [N][512] bf16
               const bf16* __restrict__ W1,   // [2048][512] bf16
               const bf16* __restrict__ W2,   // [512][2048] bf16
               const float* __restrict__ b1,  // [2048]
               const float* __restrict__ b2,  // [512]
               float* __restrict__ xio)       // [N][512] f32, in/out
{
    __shared__ bf16 hs[16 * 64 * 32];   // 64 KiB: [plane][node][32k]
    __shared__ bf16 ps[2 * 64 * 256];   // 64 KiB: [buf][node][256 ff1]

    const int tid = threadIdx.x;
    const int w = tid >> 6, l = tid & 63;
    const int node0 = blockIdx.x * 64;
    const int ml = l & 15, lh = l >> 4;

    // ---- stage h2 block: 64 chunks of 1 KiB -------------------------------
    {
        const int sr = l >> 2;                                   // 0..15
        const int sk = (((l & 3) ^ ((sr >> 1) & 3)) << 3);       // swz src chunk
#pragma unroll
        for (int j = 0; j < 8; ++j) {
            const int q = j * 8 + w;                             // 0..63
            const int pl = q >> 2, rg = q & 3;
            const bf16* src = h2 + (size_t)(node0 + rg * 16 + sr) * 512
                            + pl * 32 + sk;
            async_copy16(src, &hs[q << 9]);
        }
    }
    asm volatile("s_waitcnt vmcnt(0)" ::: "memory");
    __syncthreads();

    const int rdk = ((lh ^ ((ml >> 1) & 3)) << 3);   // swizzled k-chunk (elems)

    f32x4 acc2[4][4];
#pragma unroll
    for (int i = 0; i < 4; ++i)
#pragma unroll
        for (int j = 0; j < 4; ++j) acc2[i][j] = (f32x4)(0.f);

    for (int s = 0; s < 8; ++s) {
        // ---------------- p-phase (wave-private) --------------------------
        f32x4 pacc[2][4];
#pragma unroll
        for (int i = 0; i < 2; ++i)
#pragma unroll
            for (int j = 0; j < 4; ++j) pacc[i][j] = (f32x4)(0.f);

        const bf16* w1base = W1 + (size_t)(s * 256 + w * 32) * 512;
#pragma unroll
        for (int kt = 0; kt < 8; ++kt) {          // BK=64 over K=512
            bf16x8 afp[2][2], bfp[4][2];
#pragma unroll
            for (int mi = 0; mi < 2; ++mi)
#pragma unroll
                for (int ks = 0; ks < 2; ++ks)
                    afp[mi][ks] = *(const bf16x8*)(w1base
                        + (size_t)(mi * 16 + ml) * 512 + kt * 64 + ks * 32 + lh * 8);
#pragma unroll
            for (int ni = 0; ni < 4; ++ni)
#pragma unroll
                for (int ks = 0; ks < 2; ++ks)
                    bfp[ni][ks] = *(const bf16x8*)(&hs[(kt * 2 + ks) * 2048
                        + (ni * 16 + ml) * 32 + rdk]);
#pragma unroll
            for (int mi = 0; mi < 2; ++mi)
#pragma unroll
                for (int ni = 0; ni < 4; ++ni)
#pragma unroll
                    for (int ks = 0; ks < 2; ++ks)
                        pacc[mi][ni] = __builtin_amdgcn_mfma_f32_16x16x32_bf16(
                            afp[mi][ks], bfp[ni][ks], pacc[mi][ni], 0, 0, 0);
        }

        // bias + relu + bf16 pack + swizzled LDS write
        const int buf = (s & 1) << 14;
#pragma unroll
        for (int mi = 0; mi < 2; ++mi) {
            const float4 bb = *(const float4*)(b1 + s * 256 + w * 32 + mi * 16 + lh * 4);
            const float b4[4] = {bb.x, bb.y, bb.z, bb.w};
#pragma unroll
            for (int ni = 0; ni < 4; ++ni) {
                const int row = ni * 16 + ml;
                const int col = (w * 32 + mi * 16 + lh * 4) ^ ((row & 7) << 3);
                union { uint2 v; unsigned short s4[4]; } o;
#pragma unroll
                for (int r = 0; r < 4; ++r)
                    o.s4[r] = f2b(fmaxf(pacc[mi][ni][r] + b4[r], 0.f));
                *(uint2*)(&ps[buf + row * 256 + col]) = o.v;
            }
        }
        __syncthreads();   // p complete for this super-iter

        // ---------------- out-phase ---------------------------------------
        const bf16* w2base = W2 + (size_t)(w * 64) * 2048 + s * 256;
#pragma unroll
        for (int kt2 = 0; kt2 < 8; ++kt2) {       // 256 ff1-k in tiles of 32
            bf16x8 af2[4], bf2[4];
#pragma unroll
            for (int of = 0; of < 4; ++of)
                af2[of] = *(const bf16x8*)(w2base
                    + (size_t)(of * 16 + ml) * 2048 + kt2 * 32 + lh * 8);
#pragma unroll
            for (int nf = 0; nf < 4; ++nf) {
                const int row = nf * 16 + ml;
                const int col = (kt2 * 32 + lh * 8) ^ ((row & 7) << 3);
                bf2[nf] = *(const bf16x8*)(&ps[buf + row * 256 + col]);
            }
#pragma unroll
            for (int of = 0; of < 4; ++of)
#pragma unroll
                for (int nf = 0; nf < 4; ++nf)
                    acc2[of][nf] = __builtin_amdgcn_mfma_f32_16x16x32_bf16(
                        af2[of], bf2[nf], acc2[of][nf], 0, 0, 0);
        }
        __syncthreads();   // ps[buf] readers done before s+2 overwrites
    }

    // ---------------- epilogue: out = acc2 + x2 + b2 -----------------------
#pragma unroll
    for (int of = 0; of < 4; ++of) {
        const int oc0 = w * 64 + of * 16 + lh * 4;
        const float4 bb = *(const float4*)(b2 + oc0);
#pragma unroll
        for (int nf = 0; nf < 4; ++nf) {
            const int node = node0 + nf * 16 + ml;
            float4* p = (float4*)(xio + (size_t)node * 512 + oc0);
            const float4 r = *p;
            float4 o;
            o.x = acc2[of][nf][0] + r.x + bb.x;
            o.y = acc2[of][nf][1] + r.y + bb.y;
            o.z = acc2[of][nf][2] + r.z + bb.z;
            o.w = acc2[of][nf][3] + r.w + bb.w;
            *p = o;
        }
    }
}

// ---------------------------------------------------------------------------
extern "C" void kernel_launch(void* const* d_in, const int* in_sizes, int n_in,
                              void* d_out, int out_size, void* d_ws, size_t ws_size,
                              hipStream_t stream)
{
    const float* x   = (const float*)d_in[0];
    const float* Wq  = (const float*)d_in[1];
    const float* bq  = (const float*)d_in[2];
    const float* Wk  = (const float*)d_in[3];
    const float* bk  = (const float*)d_in[4];
    const float* Wv  = (const float*)d_in[5];
    const float* bv  = (const float*)d_in[6];
    const float* Wo  = (const float*)d_in[7];
    const float* bo  = (const float*)d_in[8];
    const float* W1  = (const float*)d_in[9];
    const float* b1  = (const float*)d_in[10];
    const float* W2  = (const float*)d_in[11];
    const float* b2  = (const float*)d_in[12];
    const float* g1  = (const float*)d_in[13];
    const float* be1 = (const float*)d_in[14];
    const float* g2  = (const float*)d_in[15];
    const float* be2 = (const float*)d_in[16];

    const int N = 65536;

    bf16* Wqb = (bf16*)d_ws;
    bf16* Wkb = Wqb + 262144;
    bf16* Wvb = Wkb + 262144;
    bf16* Wob = Wvb + 262144;
    bf16* W1b = Wob + 262144;
    bf16* W2b = W1b + 1048576;
    const size_t wts_bytes = 6ull * 1024 * 1024;
    bf16* t64 = (bf16*)((char*)d_ws + wts_bytes);
    const size_t t64_bytes = (size_t)N * 512 * 2;   // 64 MiB
    bf16* cb  = (bf16*)((char*)d_ws + wts_bytes + t64_bytes);
    const size_t used = wts_bytes + t64_bytes;
    const size_t avail = ws_size > used ? ws_size - used : 0;
    // cb now only holds qkv chunks: Nc*1536*2 bytes.
    int Nc = 32768;
    while (Nc > 256 && (size_t)Nc * 3072 > avail) Nc >>= 1;

    float* x2 = (float*)d_out;
    dim3 blk(256);
    dim3 blk5(512);

    // 0. convert weights f32 -> bf16
    cvt_kernel<<<262144 / 2048, blk, 0, stream>>>(Wq, Wqb);
    cvt_kernel<<<262144 / 2048, blk, 0, stream>>>(Wk, Wkb);
    cvt_kernel<<<262144 / 2048, blk, 0, stream>>>(Wv, Wvb);
    cvt_kernel<<<262144 / 2048, blk, 0, stream>>>(Wo, Wob);
    cvt_kernel<<<1048576 / 2048, blk, 0, stream>>>(W1, W1b);
    cvt_kernel<<<1048576 / 2048, blk, 0, stream>>>(W2, W2b);

    // 1. h = LN1(x) -> t64 (bf16)
    ln_kernel<<<N / 4, blk, 0, stream>>>(x, g1, be1, t64);

    // 2+3. per chunk: qkv_c = h_c @ [Wq|Wk|Wv]^T + bias ; attnout_c = attn(qkv_c)
    for (int r0 = 0; r0 < N; r0 += Nc) {
        gemm_bt<EPI_PLAIN><<<dim3(6, Nc / 256), blk5, 0, stream>>>(
            t64 + (size_t)r0 * 512, Wqb, Wkb, Wvb, bq, bk, bv, nullptr,
            cb, 512, 512, 1536);
        attn_kernel<<<Nc / 4, blk, 0, stream>>>(cb, t64 + (size_t)r0 * 512);
    }

    // 4. x2 = x + attnout @ Wo^T + bo   -> d_out (f32)
    gemm_bt<EPI_RES><<<dim3(2, N / 256), blk5, 0, stream>>>(
        t64, Wob, Wob, Wob, bo, bo, bo, x, x2, 512, 512, 512);

    // 5. h2 = LN2(x2) -> t64 (bf16)
    ln_kernel<<<N / 4, blk, 0, stream>>>(x2, g2, be2, t64);

    // 6+7. fused FFN: x2 += relu(h2 @ W1^T + b1) @ W2^T + b2  (in-place)
    ffn_fused<<<N / 64, blk5, 0, stream>>>(t64, W1b, W2b, b1, b2, x2);
}